// Round 6
// baseline (102.236 us; speedup 1.0000x reference)
//
#include <hip/hip_runtime.h>
#include <stdint.h>

typedef int i32x4 __attribute__((ext_vector_type(4)));
typedef float f32x4 __attribute__((ext_vector_type(4)));

#define N_IMG 32
#define C_IN 256
#define H_IN 56
#define W_IN 56
#define K_OUT 256
#define H_OUT 54
#define W_OUT 54
#define HW_OUT 2916          // 54*54
#define M_PIX 93312          // 32*2916 = 384 * 243
#define CHW_OUT 746496       // 256*2916

#define BM 384               // pixel rows per block (M_PIX/BM = 243 exact, <=1 block/CU)
#define NSTEP 36             // 9 taps x 4 ch-quarters (BK=64 i8)

#define XT_BYTES ((size_t)N_IMG * H_IN * W_IN * C_IN)   // 25,690,112 (i8 NHWC)
#define WT_BYTES ((size_t)9 * K_OUT * C_IN)             // 589,824   (i8 [tap][k][c])

// LDS: 3 buffers x (A 384x64=24576 + B 256x64=16384) = 3 x 40960 = 122880 B
#define BUF_STRIDE 40960
#define BOFF 24576

// -------- fused transforms: x NCHW i32 -> NHWC i8 ; w OIHW f32 -> [tap][k][c] i8 ----
__global__ __launch_bounds__(256) void xform(const int* __restrict__ x,
                                             const float* __restrict__ w,
                                             unsigned char* __restrict__ xt,
                                             unsigned char* __restrict__ wt) {
    const int bid = blockIdx.x;
    if (bid < N_IMG * H_IN) {
        const int n = bid / H_IN;
        const int h = bid % H_IN;
        const int c = threadIdx.x;
        const int* src = x + ((size_t)((n * C_IN + c) * H_IN + h)) * W_IN;
        unsigned char* dst = xt + ((size_t)(n * H_IN + h) * W_IN) * C_IN + c;
        #pragma unroll
        for (int w0 = 0; w0 < W_IN; w0 += 4) {
            int4 v = *(const int4*)(src + w0);
            int a[4] = {v.x, v.y, v.z, v.w};
            #pragma unroll
            for (int j = 0; j < 4; ++j) {
                int q = a[j] < 0 ? 0 : (a[j] > 7 ? 7 : a[j]);
                dst[(size_t)(w0 + j) * C_IN] = (unsigned char)q;
            }
        }
    } else {
        const int k = bid - N_IMG * H_IN;
        const int c = threadIdx.x;
        const float* src = w + ((size_t)k * C_IN + c) * 9;
        #pragma unroll
        for (int rs = 0; rs < 9; ++rs) {
            int iv = (int)src[rs];   // truncation == astype(int32); values 0..6
            wt[((size_t)rs * K_OUT + k) * C_IN + c] = (unsigned char)iv;
        }
    }
}

// -------- async global->LDS (width 16) --------
__device__ __forceinline__ void gload_lds16(const void* g, void* l) {
    __builtin_amdgcn_global_load_lds(
        (const __attribute__((address_space(1))) uint32_t*)g,
        (__attribute__((address_space(3))) uint32_t*)l,
        16, 0, 0);
}

__device__ __forceinline__ unsigned lds_off(const void* p) {
    return (unsigned)(unsigned long long)(__attribute__((address_space(3))) const char*)p;
}

#define DSREAD(dst, addr) \
    asm volatile("ds_read_b128 %0, %1" : "=v"(dst) : "v"(addr))

// swizzle key for a 64B row: chunk' = chunk ^ sw(row), involution both sides
__device__ __forceinline__ int swz4(int row) { return (row ^ (row >> 2)) & 3; }

// -------- main conv (i8): BM=384 pix, BN=256 ch, BK=64 c; 8 waves of 96x128 --------
// m201-style schedule: 2 fine phases/step, counted vmcnt(5), triple-buffered LDS.
__global__ __launch_bounds__(512, 2) void conv_mfma(const unsigned char* __restrict__ xt,
                                                    const unsigned char* __restrict__ wt,
                                                    float* __restrict__ out) {
    __shared__ __align__(16) unsigned char lds[3 * BUF_STRIDE];

    const int t512 = threadIdx.x;
    const int l    = t512 & 63;
    const int wid  = t512 >> 6;
    const int wr   = wid >> 1;     // 0..3 -> 96-pixel band
    const int wc   = wid & 1;      // 0..1 -> 128-channel half
    const int mb   = blockIdx.x;   // 243 M-tiles

    // ---- staging geometry: 64B rows, 4 threads/row, slot = t&3 ----
    // round: 512 thr x 16B = 8 KB = 128 rows. A rounds 0..2 (384 rows),
    // B rounds 3..4 (256 k-rows). Both-sides swizzle chunk ^= swz4(row).
    const int slot = t512 & 3;
    const int trow = t512 >> 2;          // 0..127 within a round
    const int tb16 = t512 * 16;

    int srcA[3];   // per-thread global byte offset (pixel base + swizzled chunk)
    #pragma unroll
    for (int rnd = 0; rnd < 3; ++rnd) {
        const int r   = rnd * 128 + trow;          // row in A-tile, 0..383
        const int m   = mb * BM + r;
        const int n   = m / HW_OUT;
        const int rem = m - n * HW_OUT;
        const int oh  = rem / W_OUT;
        const int ow  = rem - oh * W_OUT;
        srcA[rnd] = ((n * H_IN + oh) * W_IN + ow) * 256 + ((slot ^ swz4(r)) << 4);
    }
    int srcB[2];
    #pragma unroll
    for (int rnd = 0; rnd < 2; ++rnd) {
        const int k = rnd * 128 + trow;            // k-row, 0..255
        srcB[rnd] = k * 256 + ((slot ^ swz4(k)) << 4);
    }

    // ---- per-lane fragment read offsets (loop-invariant) ----
    const int lrow = l & 15;
    const int g    = l >> 4;             // 16B chunk index 0..3
    unsigned aoff[6], boff[8];
    #pragma unroll
    for (int mf = 0; mf < 6; ++mf) {
        const int r = wr * 96 + mf * 16 + lrow;
        aoff[mf] = (unsigned)(r * 64 + ((g ^ swz4(r)) << 4));
    }
    #pragma unroll
    for (int nf = 0; nf < 8; ++nf) {
        const int k = wc * 128 + nf * 16 + lrow;
        boff[nf] = (unsigned)(BOFF + k * 64 + ((g ^ swz4(k)) << 4));
    }

    i32x4 acc[6][8];
    #pragma unroll
    for (int i = 0; i < 6; ++i)
        #pragma unroll
        for (int j = 0; j < 8; ++j)
            acc[i][j] = (i32x4){0, 0, 0, 0};

    const char* xb = (const char*)xt;
    const char* wb = (const char*)wt;
    const unsigned ldsb = lds_off(lds);

    // stage step T (tap=T>>2, cq=T&3) into LDS buffer at byte offset BUFO
    #define STAGE_A3(T, BUFO) do {                                          \
        const int tap_ = (T) >> 2, cq_ = (T) & 3;                           \
        const int r_ = tap_ / 3, s_ = tap_ - r_ * 3;                        \
        const int ast_ = (r_ * W_IN + s_) * 256 + cq_ * 64;                 \
        gload_lds16(xb + srcA[0] + ast_, lds + (BUFO) + tb16);              \
        gload_lds16(xb + srcA[1] + ast_, lds + (BUFO) + 8192 + tb16);       \
        gload_lds16(xb + srcA[2] + ast_, lds + (BUFO) + 16384 + tb16);      \
    } while (0)
    #define STAGE_B2(T, BUFO) do {                                          \
        const int tap_ = (T) >> 2, cq_ = (T) & 3;                           \
        const int bst_ = tap_ * (K_OUT * C_IN) + cq_ * 64;                  \
        gload_lds16(wb + srcB[0] + bst_, lds + (BUFO) + BOFF + tb16);       \
        gload_lds16(wb + srcB[1] + bst_, lds + (BUFO) + BOFF + 8192 + tb16);\
    } while (0)

    // ---- prologue: stage steps 0 and 1 ----
    STAGE_A3(0, 0);          STAGE_B2(0, 0);
    STAGE_A3(1, BUF_STRIDE); STAGE_B2(1, BUF_STRIDE);
    asm volatile("s_waitcnt vmcnt(5)" ::: "memory");   // step-0 resident
    __builtin_amdgcn_s_barrier();

    unsigned curO = 0, nxtO = BUF_STRIDE, stgO = 2 * BUF_STRIDE;

    for (int t = 0; t < NSTEP; ++t) {
        int t2 = t + 2; if (t2 >= NSTEP) t2 -= NSTEP;   // wrap: redundant, harmless
        const unsigned aB = ldsb + curO;
        i32x4 a[6], bA[4], bB[4];

        // ---------- phase 1: a0..5 + b0..3 reads, stage-A of t+2, 24 MFMA ----------
        #pragma unroll
        for (int mf = 0; mf < 6; ++mf) DSREAD(a[mf], aB + aoff[mf]);
        #pragma unroll
        for (int nf = 0; nf < 4; ++nf) DSREAD(bA[nf], aB + boff[nf]);
        STAGE_A3(t2, stgO);
        __builtin_amdgcn_s_barrier();
        asm volatile("s_waitcnt lgkmcnt(0)" ::: "memory");
        __builtin_amdgcn_sched_barrier(0);
        __builtin_amdgcn_s_setprio(1);
        #pragma unroll
        for (int mf = 0; mf < 6; ++mf)
            #pragma unroll
            for (int nf = 0; nf < 4; ++nf)
                acc[mf][nf] = __builtin_amdgcn_mfma_i32_16x16x64_i8(
                    a[mf], bA[nf], acc[mf][nf], 0, 0, 0);
        __builtin_amdgcn_s_setprio(0);
        __builtin_amdgcn_s_barrier();

        // ---------- phase 2: b4..7 reads, stage-B of t+2, 24 MFMA ----------
        #pragma unroll
        for (int nf = 0; nf < 4; ++nf) DSREAD(bB[nf], aB + boff[nf + 4]);
        STAGE_B2(t2, stgO);
        __builtin_amdgcn_s_barrier();
        asm volatile("s_waitcnt lgkmcnt(0)" ::: "memory");
        __builtin_amdgcn_sched_barrier(0);
        __builtin_amdgcn_s_setprio(1);
        #pragma unroll
        for (int mf = 0; mf < 6; ++mf)
            #pragma unroll
            for (int nf = 0; nf < 4; ++nf)
                acc[mf][nf + 4] = __builtin_amdgcn_mfma_i32_16x16x64_i8(
                    a[mf], bB[nf], acc[mf][nf + 4], 0, 0, 0);
        __builtin_amdgcn_s_setprio(0);
        // counted wait: drain step-(t+1)'s 5 loads; keep step-(t+2)'s 5 in flight
        asm volatile("s_waitcnt vmcnt(5)" ::: "memory");
        __builtin_amdgcn_s_barrier();

        const unsigned tmp = curO; curO = nxtO; nxtO = stgO; stgO = tmp;
    }

    asm volatile("s_waitcnt vmcnt(0)" ::: "memory");

    // ---- epilogue: C/D col=lane&15, row=(lane>>4)*4+reg; float4 stores ----
    // (2916 % 4 == 0 so each 4-dword group never straddles an image boundary)
    const int c16 = l & 15;
    const int p4  = (l >> 4) << 2;
    #pragma unroll
    for (int mf = 0; mf < 6; ++mf) {
        const int m   = mb * BM + wr * 96 + mf * 16 + p4;
        const int n   = m / HW_OUT;
        const int rem = m - n * HW_OUT;
        float* ob = out + (size_t)n * CHW_OUT + rem;
        #pragma unroll
        for (int nf = 0; nf < 8; ++nf) {
            const int ch = wc * 128 + nf * 16 + c16;
            f32x4 v;
            #pragma unroll
            for (int j = 0; j < 4; ++j) v[j] = (float)acc[mf][nf][j];
            *(f32x4*)(ob + (size_t)ch * HW_OUT) = v;
        }
    }
    #undef STAGE_A3
    #undef STAGE_B2
}

// -------- fallback (only if ws too small): naive direct conv, exact --------
__global__ __launch_bounds__(256) void conv_naive(const int* __restrict__ x,
                                                  const float* __restrict__ w,
                                                  float* __restrict__ out) {
    int idx = blockIdx.x * 256 + threadIdx.x;
    if (idx >= N_IMG * K_OUT * HW_OUT) return;
    const int wo = idx % W_OUT;
    int tmp = idx / W_OUT;
    const int ho = tmp % H_OUT; tmp /= H_OUT;
    const int k = tmp % K_OUT;
    const int n = tmp / K_OUT;
    float acc = 0.f;
    for (int c = 0; c < C_IN; ++c) {
        const int* xp = x + ((size_t)((n * C_IN + c) * H_IN + ho)) * W_IN + wo;
        const float* wp = w + ((size_t)(k * C_IN + c)) * 9;
        #pragma unroll
        for (int r = 0; r < 3; ++r)
            #pragma unroll
            for (int s = 0; s < 3; ++s) {
                int xv = xp[r * W_IN + s];
                xv = xv < 0 ? 0 : (xv > 7 ? 7 : xv);
                acc += (float)xv * (float)(int)wp[r * 3 + s];
            }
    }
    out[idx] = acc;
}

extern "C" void kernel_launch(void* const* d_in, const int* in_sizes, int n_in,
                              void* d_out, int out_size, void* d_ws, size_t ws_size,
                              hipStream_t stream) {
    const int*   x = (const int*)d_in[0];
    const float* w = (const float*)d_in[1];
    float* out = (float*)d_out;

    const size_t need = XT_BYTES + WT_BYTES;   // ~26.3 MB
    if (ws_size >= need) {
        unsigned char* xt = (unsigned char*)d_ws;
        unsigned char* wt = (unsigned char*)((char*)d_ws + XT_BYTES);
        hipLaunchKernelGGL(xform, dim3(N_IMG * H_IN + K_OUT), dim3(256), 0, stream,
                           x, w, xt, wt);
        hipLaunchKernelGGL(conv_mfma, dim3(M_PIX / BM), dim3(512), 0, stream,
                           xt, wt, out);
    } else {
        const int total = N_IMG * K_OUT * HW_OUT;
        hipLaunchKernelGGL(conv_naive, dim3((total + 255) / 256), dim3(256), 0, stream, x, w, out);
    }
}